// Round 2
// baseline (350.578 us; speedup 1.0000x reference)
//
#include <hip/hip_runtime.h>
#include <hip/hip_bf16.h>
#include <cstdint>
#include <cstddef>

#define BN_EPS 1e-5f

typedef short short8 __attribute__((ext_vector_type(8)));
typedef float float16 __attribute__((ext_vector_type(16)));
typedef unsigned short ushort_t;

__device__ __forceinline__ float bf2f(ushort_t u) {
  return __uint_as_float(((unsigned int)u) << 16);
}
__device__ __forceinline__ ushort_t f2bf(float f) {
  unsigned int u = __float_as_uint(f);
  u += 0x7FFFu + ((u >> 16) & 1u);
  return (ushort_t)(u >> 16);
}

// ------------------------------------------------------------------
// PFN stats via moments: S = sum x (9), M = sum x x^T (45 upper-tri).
// ------------------------------------------------------------------

__global__ __launch_bounds__(512) void pillar_moments(
    const float* __restrict__ pillars, float* __restrict__ mom) {
  float S[9], M[45];
#pragma unroll
  for (int i = 0; i < 9; ++i) S[i] = 0.f;
#pragma unroll
  for (int i = 0; i < 45; ++i) M[i] = 0.f;
  const int t = blockIdx.x * 512 + threadIdx.x;
  const int NTH = 128 * 512;
  for (long r = t; r < 640000; r += NTH) {
    float x[9];
    const float* rp = pillars + r * 9;
#pragma unroll
    for (int d = 0; d < 9; ++d) x[d] = rp[d];
    int k = 0;
#pragma unroll
    for (int i = 0; i < 9; ++i) {
      S[i] += x[i];
#pragma unroll
      for (int j = i; j < 9; ++j) { M[k] += x[i] * x[j]; ++k; }
    }
  }
#pragma unroll
  for (int i = 0; i < 9; ++i)
#pragma unroll
    for (int o = 32; o > 0; o >>= 1) S[i] += __shfl_xor(S[i], o);
#pragma unroll
  for (int i = 0; i < 45; ++i)
#pragma unroll
    for (int o = 32; o > 0; o >>= 1) M[i] += __shfl_xor(M[i], o);
  __shared__ float red[8 * 54];
  int lane = threadIdx.x & 63, wv = threadIdx.x >> 6;
  if (lane == 0) {
#pragma unroll
    for (int i = 0; i < 9; ++i) red[wv * 54 + i] = S[i];
#pragma unroll
    for (int i = 0; i < 45; ++i) red[wv * 54 + 9 + i] = M[i];
  }
  __syncthreads();
  if (threadIdx.x < 54) {
    float s = 0.f;
#pragma unroll
    for (int w8 = 0; w8 < 8; ++w8) s += red[w8 * 54 + threadIdx.x];
    atomicAdd(&mom[threadIdx.x], s);
  }
}

__global__ void pfn_finalize(const float* __restrict__ mom,
                             const float* __restrict__ lin_w,
                             const float* __restrict__ lin_b,
                             const float* __restrict__ g, const float* __restrict__ b,
                             float* __restrict__ ss) {
  int c = threadIdx.x;
  double w[9], S[9];
#pragma unroll
  for (int d = 0; d < 9; ++d) {
    w[d] = (double)lin_w[c * 9 + d];
    S[d] = (double)mom[d];
  }
  double wS = 0.0;
#pragma unroll
  for (int d = 0; d < 9; ++d) wS += w[d] * S[d];
  double wMw = 0.0;
  int k = 0;
#pragma unroll
  for (int i = 0; i < 9; ++i)
#pragma unroll
    for (int j = i; j < 9; ++j) {
      double m = (double)mom[9 + k];
      wMw += (i == j ? 1.0 : 2.0) * w[i] * w[j] * m;
      ++k;
    }
  const double N = 640000.0;
  double bc = (double)lin_b[c];
  double mean = (wS + N * bc) / N;
  double ey2 = (wMw + 2.0 * bc * wS + N * bc * bc) / N;
  double var = ey2 - mean * mean;
  if (var < 0.0) var = 0.0;
  double inv = 1.0 / sqrt(var + (double)BN_EPS);
  double sc = (double)g[c] * inv;
  ss[c] = (float)sc;
  ss[c + 64] = (float)((double)b[c] - mean * sc);
}

__global__ __launch_bounds__(256) void pfn_feats(
    const float* __restrict__ pillars, const float* __restrict__ lin_w,
    const float* __restrict__ lin_b, const float* __restrict__ ss,
    ushort_t* __restrict__ feats) {
  __shared__ float s_p[1152];
  int tid = threadIdx.x;
  int c = tid & 63, pe = tid >> 6;
  long pb = (long)blockIdx.x * 4;
  for (int i = tid; i < 1152; i += 256) s_p[i] = pillars[pb * 288 + i];
  float w[9];
#pragma unroll
  for (int d = 0; d < 9; ++d) w[d] = lin_w[c * 9 + d];
  float bl = lin_b[c];
  float sc = ss[c], sh = ss[c + 64];
  __syncthreads();
  const float* pp = &s_p[pe * 288];
  float m = -1e30f;
#pragma unroll 4
  for (int n = 0; n < 32; ++n) {
    float y = bl;
#pragma unroll
    for (int d = 0; d < 9; ++d) y += pp[n * 9 + d] * w[d];
    float v = fmaxf(y * sc + sh, 0.f);
    m = fmaxf(m, v);
  }
  feats[(pb + pe) * 64 + c] = f2bf(m);
}

// ------------------------------------------------------------------
// Scatter winner map (numpy last-write-wins)
// ------------------------------------------------------------------

__global__ void scatter_winner(const int* __restrict__ coords, int* __restrict__ winner,
                               int P) {
  int p = blockIdx.x * 256 + threadIdx.x;
  if (p >= P) return;
  int y = coords[p * 3 + 1], x = coords[p * 3 + 2];
  if (y >= 0 && y < 666 && x >= 0 && x < 666) atomicMax(&winner[y * 666 + x], p);
}

// ------------------------------------------------------------------
// Weight prep (merged): OIHW fp32 -> fragment-ordered bf16 (Kc=32 layout)
// ------------------------------------------------------------------

__device__ __forceinline__ void prep_one(const float* __restrict__ w,
                                         ushort_t* __restrict__ w2, int C, int N,
                                         int Ntg, int chunks, int u) {
  int total = chunks * 9 * 2 * Ntg * 64;
  if (u >= total) return;
  int l = u & 63;
  int g = u >> 6;
  int ntg = g % Ntg;
  int g2 = g / Ntg;
  int s = g2 & 1;
  int g3 = g2 >> 1;
  int pos = g3 % 9;
  int cc = g3 / 9;
  int n = ntg * 32 + (l & 31);
  int c0 = cc * 32 + s * 16 + (l >> 5) * 8;
  ushort_t o8[8];
#pragma unroll
  for (int j = 0; j < 8; ++j) {
    int c = c0 + j;
    float v = (n < N && c < C) ? w[((size_t)n * C + c) * 9 + pos] : 0.f;
    o8[j] = f2bf(v);
  }
  *(uint4*)&w2[(size_t)u * 8] = *(const uint4*)o8;
}

__device__ __forceinline__ void prep_head_one(const float* __restrict__ hb,
                                              const float* __restrict__ hc,
                                              ushort_t* __restrict__ w2, int u) {
  int total = 8 * 9 * 2 * 64;
  if (u >= total) return;
  int l = u & 63;
  int g = u >> 6;
  int s = g & 1;
  int g3 = g >> 1;
  int pos = g3 % 9;
  int cc = g3 / 9;
  int n = l & 31;
  int c0 = cc * 32 + s * 16 + (l >> 5) * 8;
  ushort_t o8[8];
#pragma unroll
  for (int j = 0; j < 8; ++j) {
    int c = c0 + j;
    float v = 0.f;
    if (n < 21) v = hb[((size_t)n * 256 + c) * 9 + pos];
    else if (n < 24) v = hc[((size_t)(n - 21) * 256 + c) * 9 + pos];
    o8[j] = f2bf(v);
  }
  *(uint4*)&w2[(size_t)u * 8] = *(const uint4*)o8;
}

// grid 234 x 256
__global__ void prep_all(const float* __restrict__ c1_w, const float* __restrict__ c2_w,
                         const float* __restrict__ h1_w, const float* __restrict__ hb_w,
                         const float* __restrict__ hc_w, ushort_t* __restrict__ w2c1,
                         ushort_t* __restrict__ w2c2, ushort_t* __restrict__ w2h1,
                         ushort_t* __restrict__ w2hd) {
  int b = blockIdx.x;
  int t = threadIdx.x;
  if (b < 18) prep_one(c1_w, w2c1, 64, 64, 2, 2, b * 256 + t);
  else if (b < 54) prep_one(c2_w, w2c2, 64, 128, 4, 2, (b - 18) * 256 + t);
  else if (b < 198) prep_one(h1_w, w2h1, 128, 256, 8, 4, (b - 54) * 256 + t);
  else prep_head_one(hb_w, hc_w, w2hd, (b - 198) * 256 + t);
}

// ------------------------------------------------------------------
// BN coef publish
// ------------------------------------------------------------------

__global__ void bn_make_coefs(const float* __restrict__ acc, const float* __restrict__ g,
                              const float* __restrict__ b, float invN,
                              float* __restrict__ coef, int C) {
  int c = threadIdx.x;
  if (c >= C) return;
  float m = acc[c] * invN;
  float v = fmaxf(acc[c + 256] * invN - m * m, 0.f);
  float sc = g[c] * rsqrtf(v + BN_EPS);
  coef[c] = sc;
  coef[C + c] = b[c] - m * sc;
}

// ------------------------------------------------------------------
// Implicit-GEMM 3x3 conv via v_mfma_f32_32x32x16_bf16.
// MODE 1: BN-stage from raw unpadded HWC: relu(x*sc+sh), bounds->0.
// MODE 2: gather-stage (conv1): winner[cell] -> bf16 feats row, miss->0.
// HEAD: z = K-split; coalesced fp32 partials. STATS: fused BN stats.
// POOL: fused raw 2x2 max-pool (BN scale > 0 -> monotone).
// SPLIT: stage K=16 half-chunks per phase -> per-block LDS ~31 KB so
// 4-5 blocks co-reside per CU (cross-block overlap hides stage latency;
// R0 showed occupancy, not barrier count, is the lever).
// ------------------------------------------------------------------

template <int NT, int WAVES, int MODE, bool HEAD, bool STATS, bool POOL, bool SPLIT>
__global__ __launch_bounds__(WAVES * 64, SPLIT ? 4 : (WAVES == 8 ? 4 : 3)) void conv_mfma(
    const ushort_t* __restrict__ in, const int* __restrict__ winner,
    const ushort_t* __restrict__ feats, const ushort_t* __restrict__ w2,
    const float* __restrict__ bias, const float* __restrict__ bias2,
    const float* __restrict__ coef_in, ushort_t* __restrict__ obf,
    float* __restrict__ hpart, float* __restrict__ statacc, int W, int H, int C,
    int nchunks, int Ntg) {
  constexpr int NTHREADS = WAVES * 64;
  constexpr int CPP = SPLIT ? 16 : 32;   // shorts per staged position
  constexpr int SGN = SPLIT ? 2 : 4;     // staging channel-groups (8ch each)
  constexpr int SIN = (WAVES + 2) * 66 * CPP;        // shorts
  constexpr int SWC = (SPLIT ? 9 : 18) * NT * 512;   // shorts
  __shared__ ushort_t s_all[SIN + SWC];
  ushort_t* s_in = s_all;
  ushort_t* s_w = s_all + SIN;
  const int tid = threadIdx.x;
  const int lane = tid & 63, wv = tid >> 6;
  const int lc = lane & 31, lh = lane >> 5;
  const int x0 = blockIdx.x * 64, y0 = blockIdx.y * WAVES;
  const int z = blockIdx.z;
  const int cc0 = HEAD ? z * nchunks : 0;
  const int z_oc = HEAD ? 0 : z;

  // per-lane A-address precompute (shorts)
  int pc[2][2][3];
#pragma unroll
  for (int s = 0; s < 2; ++s)
#pragma unroll
    for (int Mt = 0; Mt < 2; ++Mt)
#pragma unroll
      for (int kx = 0; kx < 3; ++kx) {
        int col = Mt * 32 + kx + lc;
        if (SPLIT) {
          int q = lh ^ (col & 1);
          pc[s][Mt][kx] = col * 16 + q * 8;
        } else {
          int q = (2 * s + lh) ^ ((col >> 1) & 3);
          pc[s][Mt][kx] = col * 32 + q * 8;
        }
      }

  // ---- hoisted staging descriptors ----
  const int sg = tid & (SGN - 1);
  const int tpos = tid / SGN;
  constexpr int TPOS = NTHREADS / SGN;
  constexpr int NPOS = (WAVES + 2) * 66;
  constexpr int NIT = (NPOS + TPOS - 1) / TPOS;
  int ldst[NIT], gsrc[NIT];
#pragma unroll
  for (int it = 0; it < NIT; ++it) {
    ldst[it] = -1;
    gsrc[it] = -1;
    int p = tpos + it * TPOS;
    if (p < NPOS) {
      int r = p / 66, col = p - r * 66;
      int f = SPLIT ? (sg ^ (col & 1)) : (sg ^ ((col >> 1) & 3));
      ldst[it] = (r * 66 + col) * CPP + f * 8;
      int gy = y0 - 1 + r, gx = x0 - 1 + col;
      if (gy >= 0 && gy < H && gx >= 0 && gx < W) {
        if (MODE == 2) {
          int pw = winner[gy * 666 + gx];
          if (pw >= 0) gsrc[it] = pw * 64 + sg * 8;
        } else {
          gsrc[it] = (gy * W + gx) * C + sg * 8;
        }
      }
    }
  }

  float bv[NT];
#pragma unroll
  for (int nt = 0; nt < NT; ++nt) {
    if (HEAD) {
      bv[nt] = (z == 0) ? (lc < 21 ? bias[lc] : (lc < 24 ? bias2[lc - 21] : 0.f)) : 0.f;
    } else {
      bv[nt] = bias[(z * NT + nt) * 32 + lc];
    }
  }
  float16 acc[2][NT];
#pragma unroll
  for (int Mt = 0; Mt < 2; ++Mt)
#pragma unroll
    for (int nt = 0; nt < NT; ++nt)
#pragma unroll
      for (int r = 0; r < 16; ++r) acc[Mt][nt][r] = bv[nt];

  // ---- staging / compute helpers ----
  auto stage_in = [&](int ccg, int sh) {
    const int off = ccg * 32 + (SPLIT ? sh * 16 : 0);
    if (MODE == 2) {
#pragma unroll
      for (int it = 0; it < NIT; ++it) {
        if (ldst[it] < 0) continue;
        uint4 v = make_uint4(0, 0, 0, 0);
        if (gsrc[it] >= 0) v = *(const uint4*)&feats[gsrc[it] + off];
        *(uint4*)&s_in[ldst[it]] = v;
      }
    } else {  // MODE 1
      float sc8[8], sh8[8];
      {
        int ch = off + sg * 8;
        float4 a0 = *(const float4*)&coef_in[ch];
        float4 a1 = *(const float4*)&coef_in[ch + 4];
        float4 b0 = *(const float4*)&coef_in[C + ch];
        float4 b1 = *(const float4*)&coef_in[C + ch + 4];
        sc8[0] = a0.x; sc8[1] = a0.y; sc8[2] = a0.z; sc8[3] = a0.w;
        sc8[4] = a1.x; sc8[5] = a1.y; sc8[6] = a1.z; sc8[7] = a1.w;
        sh8[0] = b0.x; sh8[1] = b0.y; sh8[2] = b0.z; sh8[3] = b0.w;
        sh8[4] = b1.x; sh8[5] = b1.y; sh8[6] = b1.z; sh8[7] = b1.w;
      }
#pragma unroll
      for (int it = 0; it < NIT; ++it) {
        if (ldst[it] < 0) continue;
        ushort_t v8[8] = {0, 0, 0, 0, 0, 0, 0, 0};
        if (gsrc[it] >= 0) {
          uint4 raw = *(const uint4*)&in[gsrc[it] + off];
          const ushort_t* rp = (const ushort_t*)&raw;
#pragma unroll
          for (int j = 0; j < 8; ++j)
            v8[j] = f2bf(fmaxf(bf2f(rp[j]) * sc8[j] + sh8[j], 0.f));
        }
        *(uint4*)&s_in[ldst[it]] = *(const uint4*)v8;
      }
    }
  };

  auto stage_w = [&](int ccg, int sh) {
    if (SPLIT) {
      const int NWU = 9 * NT * 64;
      for (int u = tid; u < NWU; u += NTHREADS) {
        int l16 = u & 63, grp = u >> 6;
        int nt = grp % NT, pos = grp / NT;
        const ushort_t* src =
            w2 + ((size_t)((ccg * 18 + pos * 2 + sh) * Ntg + z_oc * NT + nt) * 64 + l16) * 8;
        *(uint4*)&s_w[(size_t)((pos * NT + nt) * 512 + l16 * 8)] = *(const uint4*)src;
      }
    } else {
      const int NW = NT * 1152;
      for (int u = tid; u < NW; u += NTHREADS) {
        int l16 = u & 63, grp = u >> 6;
        int nt = grp % NT, ps = grp / NT;
        const ushort_t* src =
            w2 + ((size_t)((ccg * 18 + ps) * Ntg + z_oc * NT + nt) * 64 + l16) * 8;
        *(uint4*)&s_w[(size_t)u * 8] = *(const uint4*)src;
      }
    }
  };

  auto compute_half = [&]() {  // SPLIT: one K=16 half resident
#pragma unroll
    for (int ky = 0; ky < 3; ++ky) {
      int rowoff = (wv + ky) * (66 * CPP);
#pragma unroll
      for (int kx = 0; kx < 3; ++kx) {
        const int pos = ky * 3 + kx;
        short8 Bf[NT];
#pragma unroll
        for (int nt = 0; nt < NT; ++nt)
          Bf[nt] = *(const short8*)&s_w[(pos * NT + nt) * 512 + lane * 8];
#pragma unroll
        for (int Mt = 0; Mt < 2; ++Mt) {
          short8 Af = *(const short8*)&s_in[rowoff + pc[0][Mt][kx]];
#pragma unroll
          for (int nt = 0; nt < NT; ++nt)
            acc[Mt][nt] =
                __builtin_amdgcn_mfma_f32_32x32x16_bf16(Af, Bf[nt], acc[Mt][nt], 0, 0, 0);
        }
      }
    }
  };

  auto compute_full = [&]() {  // non-split: both K=16 halves resident
#pragma unroll
    for (int ky = 0; ky < 3; ++ky) {
      int rowoff = (wv + ky) * (66 * CPP);
#pragma unroll
      for (int kx = 0; kx < 3; ++kx) {
        const int pos = ky * 3 + kx;
#pragma unroll
        for (int s = 0; s < 2; ++s) {
          short8 Bf[NT];
#pragma unroll
          for (int nt = 0; nt < NT; ++nt)
            Bf[nt] = *(const short8*)&s_w[((pos * 2 + s) * NT + nt) * 512 + lane * 8];
#pragma unroll
          for (int Mt = 0; Mt < 2; ++Mt) {
            short8 Af = *(const short8*)&s_in[rowoff + pc[s][Mt][kx]];
#pragma unroll
            for (int nt = 0; nt < NT; ++nt)
              acc[Mt][nt] =
                  __builtin_amdgcn_mfma_f32_32x32x16_bf16(Af, Bf[nt], acc[Mt][nt], 0, 0, 0);
          }
        }
      }
    }
  };

  if (SPLIT) {
    for (int cc = 0; cc < nchunks; ++cc) {
#pragma unroll
      for (int sh = 0; sh < 2; ++sh) {
        __syncthreads();
        stage_in(cc0 + cc, sh);
        stage_w(cc0 + cc, sh);
        __syncthreads();
        __builtin_amdgcn_s_setprio(1);
        compute_half();
        __builtin_amdgcn_s_setprio(0);
      }
    }
  } else {
    for (int cc = 0; cc < nchunks; ++cc) {
      const int ccg = cc0 + cc;
      __syncthreads();
      stage_in(ccg, 0);
      stage_w(ccg, 0);
      __syncthreads();
      __builtin_amdgcn_s_setprio(1);
      compute_full();
      __builtin_amdgcn_s_setprio(0);
    }
  }

  // ---- epilogue ----
  const int y = y0 + wv;
  const bool yok = (y < H);
  const int Ntot = Ntg * 32;

  if (HEAD) {
    if (yok) {
      float* hp = hpart + (size_t)z * (size_t)(H * W) * 32;
#pragma unroll
      for (int Mt = 0; Mt < 2; ++Mt)
#pragma unroll
        for (int r = 0; r < 16; ++r) {
          int m = (r & 3) + 8 * (r >> 2) + 4 * lh;
          int x = x0 + Mt * 32 + m;
          if (x < W) {
            size_t sp = (size_t)y * W + x;
            hp[sp * 32 + lc] = acc[Mt][0][r];  // coalesced
          }
        }
    }
    return;
  }

  if (!POOL) {
    if (yok) {
#pragma unroll
      for (int Mt = 0; Mt < 2; ++Mt)
#pragma unroll
        for (int r = 0; r < 16; ++r) {
          int m = (r & 3) + 8 * (r >> 2) + 4 * lh;
          int x = x0 + Mt * 32 + m;
          if (x < W) {
            size_t sp = (size_t)y * W + x;
#pragma unroll
            for (int nt = 0; nt < NT; ++nt) {
              int oc = (z * NT + nt) * 32 + lc;
              obf[sp * Ntot + oc] = f2bf(acc[Mt][nt][r]);
            }
          }
        }
    }
  }

  if (STATS) {
    float s1[NT], s2[NT];
#pragma unroll
    for (int nt = 0; nt < NT; ++nt) { s1[nt] = 0.f; s2[nt] = 0.f; }
    if (yok) {
#pragma unroll
      for (int Mt = 0; Mt < 2; ++Mt)
#pragma unroll
        for (int r = 0; r < 16; ++r) {
          int m = (r & 3) + 8 * (r >> 2) + 4 * lh;
          int x = x0 + Mt * 32 + m;
          if (x < W) {
#pragma unroll
            for (int nt = 0; nt < NT; ++nt) {
              float v = acc[Mt][nt][r];
              s1[nt] += v;
              s2[nt] += v * v;
            }
          }
        }
    }
#pragma unroll
    for (int nt = 0; nt < NT; ++nt) {
      s1[nt] += __shfl_xor(s1[nt], 32);
      s2[nt] += __shfl_xor(s2[nt], 32);
    }
    __syncthreads();  // all MFMA LDS reads done; reuse s_all as fp32 scratch
    float* red = (float*)s_all;
    if (lh == 0) {
#pragma unroll
      for (int nt = 0; nt < NT; ++nt) {
        red[(wv * NT + nt) * 32 + lc] = s1[nt];
        red[WAVES * NT * 32 + (wv * NT + nt) * 32 + lc] = s2[nt];
      }
    }
    __syncthreads();
    if (wv == 0 && lh == 0) {
#pragma unroll
      for (int nt = 0; nt < NT; ++nt) {
        float a = 0.f, b = 0.f;
#pragma unroll
        for (int w8 = 0; w8 < WAVES; ++w8) {
          a += red[(w8 * NT + nt) * 32 + lc];
          b += red[WAVES * NT * 32 + (w8 * NT + nt) * 32 + lc];
        }
        int ch = (z * NT + nt) * 32 + lc;
        atomicAdd(&statacc[ch], a);
        atomicAdd(&statacc[ch + 256], b);
      }
    }
  }

  if (POOL) {
    const int OWp = W >> 1, OHp = H >> 1;
    float hm[2][NT][8];
#pragma unroll
    for (int Mt = 0; Mt < 2; ++Mt)
#pragma unroll
      for (int nt = 0; nt < NT; ++nt)
#pragma unroll
        for (int i = 0; i < 8; ++i)
          hm[Mt][nt][i] = fmaxf(acc[Mt][nt][2 * i], acc[Mt][nt][2 * i + 1]);
    __syncthreads();
    float* pl = (float*)s_all;
    if (wv & 1) {
#pragma unroll
      for (int Mt = 0; Mt < 2; ++Mt)
#pragma unroll
        for (int nt = 0; nt < NT; ++nt)
#pragma unroll
          for (int i = 0; i < 8; ++i)
            pl[((((wv >> 1) * 2 + Mt) * NT + nt) * 8 + i) * 64 + lane] = hm[Mt][nt][i];
    }
    __syncthreads();
    if (!(wv & 1)) {
      int oy = (y0 + wv) >> 1;
      if (oy < OHp) {
#pragma unroll
        for (int Mt = 0; Mt < 2; ++Mt)
#pragma unroll
          for (int i = 0; i < 8; ++i) {
            int pxl = Mt * 16 + (i >> 1) * 4 + (i & 1) + 2 * lh;
            int ox = (x0 >> 1) + pxl;
            if (ox < OWp) {
#pragma unroll
              for (int nt = 0; nt < NT; ++nt) {
                float v = fmaxf(
                    hm[Mt][nt][i],
                    pl[((((wv >> 1) * 2 + Mt) * NT + nt) * 8 + i) * 64 + lane]);
                int oc = (z * NT + nt) * 32 + lc;
                obf[((size_t)oy * OWp + ox) * Ntot + oc] = f2bf(v);
              }
            }
          }
      }
    }
  }
}

// ------------------------------------------------------------------
// Head reduce: sum nz HWC(x32) fp32 partial slices -> 24 CHW planes.
// ------------------------------------------------------------------

__global__ __launch_bounds__(256) void head_reduce(const float* __restrict__ hp,
                                                   float* __restrict__ out, int HW,
                                                   int nz) {
  __shared__ float t[256 * 33];
  int tid = threadIdx.x;
  int sp0 = blockIdx.x * 256;
  int lim = (HW - sp0) * 32;
#pragma unroll 4
  for (int i = 0; i < 32; ++i) {
    int e = i * 256 + tid;
    float s = 0.f;
    if (e < lim) {
      size_t gidx = (size_t)sp0 * 32 + e;
      for (int z = 0; z < nz; ++z) s += hp[(size_t)z * HW * 32 + gidx];
    }
    t[(e >> 5) * 33 + (e & 31)] = s;
  }
  __syncthreads();
  int sp = sp0 + tid;
  if (sp < HW) {
#pragma unroll
    for (int ch = 0; ch < 24; ++ch)
      out[(size_t)ch * HW + sp] = t[tid * 33 + ch];
  }
}

// ------------------------------------------------------------------

extern "C" void kernel_launch(void* const* d_in, const int* in_sizes, int n_in,
                              void* d_out, int out_size, void* d_ws, size_t ws_size,
                              hipStream_t stream) {
  (void)in_sizes; (void)n_in; (void)out_size; (void)ws_size;
  const float* pillars = (const float*)d_in[0];
  const int* coords = (const int*)d_in[1];
  const float* lin_w = (const float*)d_in[2];
  const float* lin_b = (const float*)d_in[3];
  const float* pfn_g = (const float*)d_in[4];
  const float* pfn_b = (const float*)d_in[5];
  const float* c1_w = (const float*)d_in[6];
  const float* c1_b = (const float*)d_in[7];
  const float* bn1_g = (const float*)d_in[8];
  const float* bn1_b = (const float*)d_in[9];
  const float* c2_w = (const float*)d_in[10];
  const float* c2_b = (const float*)d_in[11];
  const float* bn2_g = (const float*)d_in[12];
  const float* bn2_b = (const float*)d_in[13];
  const float* h1_w = (const float*)d_in[14];
  const float* h1_b = (const float*)d_in[15];
  const float* hbn_g = (const float*)d_in[16];
  const float* hbn_b = (const float*)d_in[17];
  const float* hb_w = (const float*)d_in[18];
  const float* hb_b = (const float*)d_in[19];
  const float* hc_w = (const float*)d_in[20];
  const float* hc_b = (const float*)d_in[21];
  float* out = (float*)d_out;

  // ---- workspace layout (bytes) ----
  char* ws = (char*)d_ws;
  float* mom     = (float*)(ws + 0);         // 54 floats (S[9], M[45])
  float* pfn_ss  = (float*)(ws + 512);       // 512 B
  float* bn_acc1 = (float*)(ws + 1024);      // 2048 B
  float* bn_acc2 = (float*)(ws + 3072);      // 2048 B
  float* bn_acc3 = (float*)(ws + 5120);      // 2048 B
  float* coef1   = (float*)(ws + 7168);      // 512 B
  float* coef2   = (float*)(ws + 7680);      // 1024 B
  float* coef3   = (float*)(ws + 8704);      // 2048 B
  int* winner    = (int*)(ws + 10752);       // 1774224 B
  ushort_t* feats  = (ushort_t*)(ws + 1785088);    // 20000x64 bf16 = 2560000 B
  ushort_t* c1p    = (ushort_t*)(ws + 4345088);    // 333x333x64  = 14193792 B (pooled raw)
  ushort_t* c2p    = (ushort_t*)(ws + 18538880);   // 166x166x128 = 7054336 B (pooled raw)
  ushort_t* h1out  = (ushort_t*)(ws + 25593216);   // 166x166x256 = 14108672 B (raw)
  ushort_t* w2c1   = (ushort_t*)(ws + 39701888);   // 73728 B
  ushort_t* w2c2   = (ushort_t*)(ws + 39775616);   // 147456 B
  ushort_t* w2h1   = (ushort_t*)(ws + 39923072);   // 589824 B
  ushort_t* w2hd   = (ushort_t*)(ws + 40512896);   // 147456 B
  float* hpart     = (float*)(ws + 40660352);      // 4x27556x32x4 = 14108672 B

  const int HW3 = 166 * 166;

  // ---- upfront zero-init ----
  hipMemsetAsync(ws, 0, 10752, stream);
  hipMemsetAsync(winner, 0xFF, 1774224, stream);

  // ---- weight prep (merged) ----
  prep_all<<<234, 256, 0, stream>>>(c1_w, c2_w, h1_w, hb_w, hc_w, w2c1, w2c2, w2h1,
                                    w2hd);

  // ---- PFN: moments-based stats, then feats ----
  pillar_moments<<<128, 512, 0, stream>>>(pillars, mom);
  pfn_finalize<<<1, 64, 0, stream>>>(mom, lin_w, lin_b, pfn_g, pfn_b, pfn_ss);
  pfn_feats<<<5000, 256, 0, stream>>>(pillars, lin_w, lin_b, pfn_ss, feats);

  // ---- scatter winner map ----
  scatter_winner<<<(20000 + 255) / 256, 256, 0, stream>>>(coords, winner, 20000);

  // ---- conv1: gather-staged, SPLIT K=16 phases, WAVES=4, stats+pool -> c1p ----
  conv_mfma<2, 4, 2, false, true, true, true><<<dim3(11, 167, 1), 256, 0, stream>>>(
      nullptr, winner, feats, w2c1, c1_b, nullptr, nullptr, c1p, nullptr, bn_acc1, 666,
      666, 64, 2, 2);
  bn_make_coefs<<<1, 64, 0, stream>>>(bn_acc1, bn1_g, bn1_b, 1.f / 443556.f, coef1, 64);

  // ---- conv2: BN-staged from c1p raw, SPLIT phases, WAVES=4, stats+pool -> c2p ----
  conv_mfma<2, 4, 1, false, true, true, true><<<dim3(6, 84, 2), 256, 0, stream>>>(
      c1p, nullptr, nullptr, w2c2, c2_b, nullptr, coef1, c2p, nullptr, bn_acc2, 333, 333,
      64, 2, 4);
  bn_make_coefs<<<1, 128, 0, stream>>>(bn_acc2, bn2_g, bn2_b, 1.f / 110889.f, coef2, 128);

  // ---- h1: BN-staged from c2p raw, NT=2 WAVES=4 oc-split z=4 (stats) ----
  conv_mfma<2, 4, 1, false, true, false, false><<<dim3(3, 42, 4), 256, 0, stream>>>(
      c2p, nullptr, nullptr, w2h1, h1_b, nullptr, coef2, h1out, nullptr, bn_acc3, 166,
      166, 128, 4, 8);
  bn_make_coefs<<<1, 256, 0, stream>>>(bn_acc3, hbn_g, hbn_b, 1.f / 27556.f, coef3, 256);

  // ---- heads: BN-staged from h1out raw, K-split z=4, coalesced partials ----
  conv_mfma<1, 4, 1, true, false, false, false><<<dim3(3, 42, 4), 256, 0, stream>>>(
      h1out, nullptr, nullptr, w2hd, hb_b, hc_b, coef3, nullptr, hpart, nullptr, 166,
      166, 256, 2, 1);
  head_reduce<<<(HW3 + 255) / 256, 256, 0, stream>>>(hpart, out, HW3, 4);
}

// Round 3
// 322.996 us; speedup vs baseline: 1.0854x; 1.0854x over previous
//
#include <hip/hip_runtime.h>
#include <hip/hip_bf16.h>
#include <cstdint>
#include <cstddef>

#define BN_EPS 1e-5f

typedef short short8 __attribute__((ext_vector_type(8)));
typedef float float16 __attribute__((ext_vector_type(16)));
typedef unsigned short ushort_t;

__device__ __forceinline__ float bf2f(ushort_t u) {
  return __uint_as_float(((unsigned int)u) << 16);
}
__device__ __forceinline__ ushort_t f2bf(float f) {
  unsigned int u = __float_as_uint(f);
  u += 0x7FFFu + ((u >> 16) & 1u);
  return (ushort_t)(u >> 16);
}

// async global -> LDS, 16 B per lane; dest must be wave-uniform base (+lane*16 in HW)
__device__ __forceinline__ void gload16(const ushort_t* g, ushort_t* l) {
  __builtin_amdgcn_global_load_lds(
      (const __attribute__((address_space(1))) unsigned int*)g,
      (__attribute__((address_space(3))) unsigned int*)l, 16, 0, 0);
}

// ------------------------------------------------------------------
// PFN stats via moments: S = sum x (9), M = sum x x^T (45 upper-tri).
// ------------------------------------------------------------------

__global__ __launch_bounds__(512) void pillar_moments(
    const float* __restrict__ pillars, float* __restrict__ mom) {
  float S[9], M[45];
#pragma unroll
  for (int i = 0; i < 9; ++i) S[i] = 0.f;
#pragma unroll
  for (int i = 0; i < 45; ++i) M[i] = 0.f;
  const int t = blockIdx.x * 512 + threadIdx.x;
  const int NTH = 128 * 512;
  for (long r = t; r < 640000; r += NTH) {
    float x[9];
    const float* rp = pillars + r * 9;
#pragma unroll
    for (int d = 0; d < 9; ++d) x[d] = rp[d];
    int k = 0;
#pragma unroll
    for (int i = 0; i < 9; ++i) {
      S[i] += x[i];
#pragma unroll
      for (int j = i; j < 9; ++j) { M[k] += x[i] * x[j]; ++k; }
    }
  }
#pragma unroll
  for (int i = 0; i < 9; ++i)
#pragma unroll
    for (int o = 32; o > 0; o >>= 1) S[i] += __shfl_xor(S[i], o);
#pragma unroll
  for (int i = 0; i < 45; ++i)
#pragma unroll
    for (int o = 32; o > 0; o >>= 1) M[i] += __shfl_xor(M[i], o);
  __shared__ float red[8 * 54];
  int lane = threadIdx.x & 63, wv = threadIdx.x >> 6;
  if (lane == 0) {
#pragma unroll
    for (int i = 0; i < 9; ++i) red[wv * 54 + i] = S[i];
#pragma unroll
    for (int i = 0; i < 45; ++i) red[wv * 54 + 9 + i] = M[i];
  }
  __syncthreads();
  if (threadIdx.x < 54) {
    float s = 0.f;
#pragma unroll
    for (int w8 = 0; w8 < 8; ++w8) s += red[w8 * 54 + threadIdx.x];
    atomicAdd(&mom[threadIdx.x], s);
  }
}

__global__ void pfn_finalize(const float* __restrict__ mom,
                             const float* __restrict__ lin_w,
                             const float* __restrict__ lin_b,
                             const float* __restrict__ g, const float* __restrict__ b,
                             float* __restrict__ ss) {
  int c = threadIdx.x;
  double w[9], S[9];
#pragma unroll
  for (int d = 0; d < 9; ++d) {
    w[d] = (double)lin_w[c * 9 + d];
    S[d] = (double)mom[d];
  }
  double wS = 0.0;
#pragma unroll
  for (int d = 0; d < 9; ++d) wS += w[d] * S[d];
  double wMw = 0.0;
  int k = 0;
#pragma unroll
  for (int i = 0; i < 9; ++i)
#pragma unroll
    for (int j = i; j < 9; ++j) {
      double m = (double)mom[9 + k];
      wMw += (i == j ? 1.0 : 2.0) * w[i] * w[j] * m;
      ++k;
    }
  const double N = 640000.0;
  double bc = (double)lin_b[c];
  double mean = (wS + N * bc) / N;
  double ey2 = (wMw + 2.0 * bc * wS + N * bc * bc) / N;
  double var = ey2 - mean * mean;
  if (var < 0.0) var = 0.0;
  double inv = 1.0 / sqrt(var + (double)BN_EPS);
  double sc = (double)g[c] * inv;
  ss[c] = (float)sc;
  ss[c + 64] = (float)((double)b[c] - mean * sc);
}

__global__ __launch_bounds__(256) void pfn_feats(
    const float* __restrict__ pillars, const float* __restrict__ lin_w,
    const float* __restrict__ lin_b, const float* __restrict__ ss,
    ushort_t* __restrict__ feats) {
  __shared__ float s_p[1152];
  int tid = threadIdx.x;
  int c = tid & 63, pe = tid >> 6;
  long pb = (long)blockIdx.x * 4;
  for (int i = tid; i < 1152; i += 256) s_p[i] = pillars[pb * 288 + i];
  float w[9];
#pragma unroll
  for (int d = 0; d < 9; ++d) w[d] = lin_w[c * 9 + d];
  float bl = lin_b[c];
  float sc = ss[c], sh = ss[c + 64];
  __syncthreads();
  const float* pp = &s_p[pe * 288];
  float m = -1e30f;
#pragma unroll 4
  for (int n = 0; n < 32; ++n) {
    float y = bl;
#pragma unroll
    for (int d = 0; d < 9; ++d) y += pp[n * 9 + d] * w[d];
    float v = fmaxf(y * sc + sh, 0.f);
    m = fmaxf(m, v);
  }
  feats[(pb + pe) * 64 + c] = f2bf(m);
}

// ------------------------------------------------------------------
// Scatter winner map (numpy last-write-wins)
// ------------------------------------------------------------------

__global__ void scatter_winner(const int* __restrict__ coords, int* __restrict__ winner,
                               int P) {
  int p = blockIdx.x * 256 + threadIdx.x;
  if (p >= P) return;
  int y = coords[p * 3 + 1], x = coords[p * 3 + 2];
  if (y >= 0 && y < 666 && x >= 0 && x < 666) atomicMax(&winner[y * 666 + x], p);
}

// ------------------------------------------------------------------
// Weight prep (merged): OIHW fp32 -> fragment-ordered bf16 (Kc=32 layout,
// stored as 18 K16 pos-slices per chunk)
// ------------------------------------------------------------------

__device__ __forceinline__ void prep_one(const float* __restrict__ w,
                                         ushort_t* __restrict__ w2, int C, int N,
                                         int Ntg, int chunks, int u) {
  int total = chunks * 9 * 2 * Ntg * 64;
  if (u >= total) return;
  int l = u & 63;
  int g = u >> 6;
  int ntg = g % Ntg;
  int g2 = g / Ntg;
  int s = g2 & 1;
  int g3 = g2 >> 1;
  int pos = g3 % 9;
  int cc = g3 / 9;
  int n = ntg * 32 + (l & 31);
  int c0 = cc * 32 + s * 16 + (l >> 5) * 8;
  ushort_t o8[8];
#pragma unroll
  for (int j = 0; j < 8; ++j) {
    int c = c0 + j;
    float v = (n < N && c < C) ? w[((size_t)n * C + c) * 9 + pos] : 0.f;
    o8[j] = f2bf(v);
  }
  *(uint4*)&w2[(size_t)u * 8] = *(const uint4*)o8;
}

__device__ __forceinline__ void prep_head_one(const float* __restrict__ hb,
                                              const float* __restrict__ hc,
                                              ushort_t* __restrict__ w2, int u) {
  int total = 8 * 9 * 2 * 64;
  if (u >= total) return;
  int l = u & 63;
  int g = u >> 6;
  int s = g & 1;
  int g3 = g >> 1;
  int pos = g3 % 9;
  int cc = g3 / 9;
  int n = l & 31;
  int c0 = cc * 32 + s * 16 + (l >> 5) * 8;
  ushort_t o8[8];
#pragma unroll
  for (int j = 0; j < 8; ++j) {
    int c = c0 + j;
    float v = 0.f;
    if (n < 21) v = hb[((size_t)n * 256 + c) * 9 + pos];
    else if (n < 24) v = hc[((size_t)(n - 21) * 256 + c) * 9 + pos];
    o8[j] = f2bf(v);
  }
  *(uint4*)&w2[(size_t)u * 8] = *(const uint4*)o8;
}

// grid 234 x 256
__global__ void prep_all(const float* __restrict__ c1_w, const float* __restrict__ c2_w,
                         const float* __restrict__ h1_w, const float* __restrict__ hb_w,
                         const float* __restrict__ hc_w, ushort_t* __restrict__ w2c1,
                         ushort_t* __restrict__ w2c2, ushort_t* __restrict__ w2h1,
                         ushort_t* __restrict__ w2hd) {
  int b = blockIdx.x;
  int t = threadIdx.x;
  if (b < 18) prep_one(c1_w, w2c1, 64, 64, 2, 2, b * 256 + t);
  else if (b < 54) prep_one(c2_w, w2c2, 64, 128, 4, 2, (b - 18) * 256 + t);
  else if (b < 198) prep_one(h1_w, w2h1, 128, 256, 8, 4, (b - 54) * 256 + t);
  else prep_head_one(hb_w, hc_w, w2hd, (b - 198) * 256 + t);
}

// ------------------------------------------------------------------
// BN coef publish
// ------------------------------------------------------------------

__global__ void bn_make_coefs(const float* __restrict__ acc, const float* __restrict__ g,
                              const float* __restrict__ b, float invN,
                              float* __restrict__ coef, int C) {
  int c = threadIdx.x;
  if (c >= C) return;
  float m = acc[c] * invN;
  float v = fmaxf(acc[c + 256] * invN - m * m, 0.f);
  float sc = g[c] * rsqrtf(v + BN_EPS);
  coef[c] = sc;
  coef[C + c] = b[c] - m * sc;
}

// ------------------------------------------------------------------
// BN+relu elementwise pre-pass: raw bf16 HWC -> ready bf16 HWC.
// Makes every conv input a plain tensor so the conv can stage with
// pure async global_load_lds (no reg roundtrip, no LDS writes).
// ------------------------------------------------------------------

__global__ __launch_bounds__(256) void bnrelu(const ushort_t* __restrict__ inp,
                                              const float* __restrict__ coef, int C,
                                              int L8, ushort_t* __restrict__ outp) {
  __shared__ float sc[512];
  int tid = threadIdx.x;
  for (int i = tid; i < 2 * C; i += 256) sc[i] = coef[i];
  __syncthreads();
  int t = blockIdx.x * 256 + tid;
  if (t >= L8) return;
  size_t e0 = (size_t)t * 8;
  int c0 = (t << 3) & (C - 1);
  short8 v = *(const short8*)&inp[e0];
  const ushort_t* vp = (const ushort_t*)&v;
  ushort_t o[8];
#pragma unroll
  for (int j = 0; j < 8; ++j) {
    float x = bf2f(vp[j]);
    o[j] = f2bf(fmaxf(x * sc[c0 + j] + sc[C + c0 + j], 0.f));
  }
  *(uint4*)&outp[e0] = *(const uint4*)o;
}

// ------------------------------------------------------------------
// Implicit-GEMM 3x3 conv via v_mfma_f32_32x32x16_bf16.
// All staging through async global_load_lds (16 B/lane, linear LDS dest,
// inverse bank-swizzle baked into per-lane SOURCE addresses; OOB/miss
// lanes read a zeroed scratch page). K=16 phases, 2-deep pipeline:
//   stage(ph) issued in phase ph-1; per phase: vmcnt(0)+s_barrier,
//   issue stage(ph+1) into the other buffer, MFMA burst on buf[ph&1].
// One barrier per phase, no vmem drain of in-flight next-phase loads.
// GATHER: conv1 winner->feats indirection (per-lane source addresses).
// HEAD: z = K-split, coalesced fp32 partials. STATS: fused BN stats.
// POOL: fused raw 2x2 max-pool.
// ------------------------------------------------------------------

template <int NT, int WAVES, bool GATHER, bool HEAD, bool STATS, bool POOL>
__global__ __launch_bounds__(WAVES * 64, 4) void conv_mfma(
    const ushort_t* __restrict__ in, const int* __restrict__ winner,
    const ushort_t* __restrict__ feats, const ushort_t* __restrict__ w2,
    const float* __restrict__ bias, const float* __restrict__ bias2,
    const ushort_t* __restrict__ zbuf, ushort_t* __restrict__ obf,
    float* __restrict__ hpart, float* __restrict__ statacc, int W, int H, int C,
    int nchunks, int Ntg) {
  constexpr int NTHREADS = WAVES * 64;
  constexpr int NPOS = (WAVES + 2) * 66;
  constexpr int IN_U4 = NPOS * 2;            // 2 x 16B slots per position (K=16)
  constexpr int W_U4 = 9 * NT * 64;
  constexpr int INIT = (IN_U4 + NTHREADS - 1) / NTHREADS;
  constexpr int WIT = (W_U4 + NTHREADS - 1) / NTHREADS;
  __shared__ ushort_t s_in[2][IN_U4 * 8];
  __shared__ ushort_t s_w[2][W_U4 * 8];
  const int tid = threadIdx.x;
  const int lane = tid & 63, wv = tid >> 6;
  const int lc = lane & 31, lh = lane >> 5;
  const int x0 = blockIdx.x * 64, y0 = blockIdx.y * WAVES;
  const int z = blockIdx.z;
  const int cc0 = HEAD ? z * nchunks : 0;
  const int z_oc = HEAD ? 0 : z;

  // A-fragment read offsets (shorts): pos p at p*16, slot g=lh^(col&1)
  int pc[2][3];
#pragma unroll
  for (int Mt = 0; Mt < 2; ++Mt)
#pragma unroll
    for (int kx = 0; kx < 3; ++kx) {
      int col = Mt * 32 + kx + lc;
      pc[Mt][kx] = col * 16 + (lh ^ (col & 1)) * 8;
    }

  // ---- hoisted per-lane staging source descriptors ----
  // LDS u4-slot d holds: position p=d>>1, phys slot g=d&1, channel-group
  // cg = g ^ (col&1)  (inverse of the read swizzle).
  const ushort_t* isrc[INIT];
#pragma unroll
  for (int it = 0; it < INIT; ++it) {
    isrc[it] = zbuf;
    int d = it * NTHREADS + tid;
    if (d < IN_U4) {
      int p = d >> 1, g = d & 1;
      int r = p / 66, col = p - r * 66;
      int cg = g ^ (col & 1);
      int gy = y0 - 1 + r, gx = x0 - 1 + col;
      if (gy >= 0 && gy < H && gx >= 0 && gx < W) {
        if (GATHER) {
          int pw = winner[gy * 666 + gx];
          if (pw >= 0) isrc[it] = feats + pw * 64 + cg * 8;
        } else {
          isrc[it] = in + (size_t)(gy * W + gx) * C + cg * 8;
        }
      }
    }
  }
  int wof[WIT];
#pragma unroll
  for (int it = 0; it < WIT; ++it) {
    wof[it] = 0;
    int d = it * NTHREADS + tid;
    if (d < W_U4) {
      int grp = d >> 6, l16 = d & 63;
      int pos = grp / NT, nt = grp % NT;
      wof[it] = (pos * 2 * Ntg + z_oc * NT + nt) * 512 + l16 * 8;
    }
  }

  float bv[NT];
#pragma unroll
  for (int nt = 0; nt < NT; ++nt) {
    if (HEAD) {
      bv[nt] = (z == 0) ? (lc < 21 ? bias[lc] : (lc < 24 ? bias2[lc - 21] : 0.f)) : 0.f;
    } else {
      bv[nt] = bias[(z * NT + nt) * 32 + lc];
    }
  }
  float16 acc[2][NT];
#pragma unroll
  for (int Mt = 0; Mt < 2; ++Mt)
#pragma unroll
    for (int nt = 0; nt < NT; ++nt)
#pragma unroll
      for (int r = 0; r < 16; ++r) acc[Mt][nt][r] = bv[nt];

  auto stage = [&](int ph, int b) {
    int ccg = cc0 + (ph >> 1), sh = ph & 1;
    int coff = ccg * 32 + sh * 16;
#pragma unroll
    for (int it = 0; it < INIT; ++it) {
      int d = it * NTHREADS + tid;
      if (d < IN_U4)
        gload16(isrc[it] + coff, &s_in[b][(size_t)(it * NTHREADS + wv * 64) * 8]);
    }
    int wbase = (ccg * 18 + sh) * Ntg * 512;
#pragma unroll
    for (int it = 0; it < WIT; ++it) {
      int d = it * NTHREADS + tid;
      if (d < W_U4)
        gload16(w2 + wbase + wof[it], &s_w[b][(size_t)(it * NTHREADS + wv * 64) * 8]);
    }
  };

  auto compute_phase = [&](int b) {
#pragma unroll
    for (int ky = 0; ky < 3; ++ky) {
      const ushort_t* rowp = &s_in[b][(wv + ky) * (66 * 16)];
#pragma unroll
      for (int kx = 0; kx < 3; ++kx) {
        const int pos = ky * 3 + kx;
        short8 Bf[NT];
#pragma unroll
        for (int nt = 0; nt < NT; ++nt)
          Bf[nt] = *(const short8*)&s_w[b][(pos * NT + nt) * 512 + lane * 8];
#pragma unroll
        for (int Mt = 0; Mt < 2; ++Mt) {
          short8 Af = *(const short8*)&rowp[pc[Mt][kx]];
#pragma unroll
          for (int nt = 0; nt < NT; ++nt)
            acc[Mt][nt] =
                __builtin_amdgcn_mfma_f32_32x32x16_bf16(Af, Bf[nt], acc[Mt][nt], 0, 0, 0);
        }
      }
    }
  };

  const int nph = nchunks * 2;
  stage(0, 0);
  for (int ph = 0; ph < nph; ++ph) {
    // own-wave loads for phase ph done; barrier publishes all waves' writes.
    asm volatile("s_waitcnt vmcnt(0)\n\ts_barrier" ::: "memory");
    if (ph + 1 < nph) stage(ph + 1, (ph + 1) & 1);
    __builtin_amdgcn_s_setprio(1);
    compute_phase(ph & 1);
    __builtin_amdgcn_s_setprio(0);
  }

  // ---- epilogue ----
  const int y = y0 + wv;
  const bool yok = (y < H);
  const int Ntot = Ntg * 32;

  if (HEAD) {
    if (yok) {
      float* hp = hpart + (size_t)z * (size_t)(H * W) * 32;
#pragma unroll
      for (int Mt = 0; Mt < 2; ++Mt)
#pragma unroll
        for (int r = 0; r < 16; ++r) {
          int m = (r & 3) + 8 * (r >> 2) + 4 * lh;
          int x = x0 + Mt * 32 + m;
          if (x < W) {
            size_t sp = (size_t)y * W + x;
            hp[sp * 32 + lc] = acc[Mt][0][r];  // coalesced
          }
        }
    }
    return;
  }

  if (!POOL) {
    if (yok) {
#pragma unroll
      for (int Mt = 0; Mt < 2; ++Mt)
#pragma unroll
        for (int r = 0; r < 16; ++r) {
          int m = (r & 3) + 8 * (r >> 2) + 4 * lh;
          int x = x0 + Mt * 32 + m;
          if (x < W) {
            size_t sp = (size_t)y * W + x;
#pragma unroll
            for (int nt = 0; nt < NT; ++nt) {
              int oc = (z * NT + nt) * 32 + lc;
              obf[sp * Ntot + oc] = f2bf(acc[Mt][nt][r]);
            }
          }
        }
    }
  }

  if (STATS) {
    float s1[NT], s2[NT];
#pragma unroll
    for (int nt = 0; nt < NT; ++nt) { s1[nt] = 0.f; s2[nt] = 0.f; }
    if (yok) {
#pragma unroll
      for (int Mt = 0; Mt < 2; ++Mt)
#pragma unroll
        for (int r = 0; r < 16; ++r) {
          int m = (r & 3) + 8 * (r >> 2) + 4 * lh;
          int x = x0 + Mt * 32 + m;
          if (x < W) {
#pragma unroll
            for (int nt = 0; nt < NT; ++nt) {
              float v = acc[Mt][nt][r];
              s1[nt] += v;
              s2[nt] += v * v;
            }
          }
        }
    }
#pragma unroll
    for (int nt = 0; nt < NT; ++nt) {
      s1[nt] += __shfl_xor(s1[nt], 32);
      s2[nt] += __shfl_xor(s2[nt], 32);
    }
    __syncthreads();  // all MFMA LDS reads done; reuse s_in as fp32 scratch
    float* red = (float*)s_in;
    if (lh == 0) {
#pragma unroll
      for (int nt = 0; nt < NT; ++nt) {
        red[(wv * NT + nt) * 32 + lc] = s1[nt];
        red[WAVES * NT * 32 + (wv * NT + nt) * 32 + lc] = s2[nt];
      }
    }
    __syncthreads();
    if (wv == 0 && lh == 0) {
#pragma unroll
      for (int nt = 0; nt < NT; ++nt) {
        float a = 0.f, b = 0.f;
#pragma unroll
        for (int w8 = 0; w8 < WAVES; ++w8) {
          a += red[(w8 * NT + nt) * 32 + lc];
          b += red[WAVES * NT * 32 + (w8 * NT + nt) * 32 + lc];
        }
        int ch = (z * NT + nt) * 32 + lc;
        atomicAdd(&statacc[ch], a);
        atomicAdd(&statacc[ch + 256], b);
      }
    }
  }

  if (POOL) {
    const int OWp = W >> 1, OHp = H >> 1;
    float hm[2][NT][8];
#pragma unroll
    for (int Mt = 0; Mt < 2; ++Mt)
#pragma unroll
      for (int nt = 0; nt < NT; ++nt)
#pragma unroll
        for (int i = 0; i < 8; ++i)
          hm[Mt][nt][i] = fmaxf(acc[Mt][nt][2 * i], acc[Mt][nt][2 * i + 1]);
    __syncthreads();
    float* pl = (float*)s_in;
    if (wv & 1) {
#pragma unroll
      for (int Mt = 0; Mt < 2; ++Mt)
#pragma unroll
        for (int nt = 0; nt < NT; ++nt)
#pragma unroll
          for (int i = 0; i < 8; ++i)
            pl[((((wv >> 1) * 2 + Mt) * NT + nt) * 8 + i) * 64 + lane] = hm[Mt][nt][i];
    }
    __syncthreads();
    if (!(wv & 1)) {
      int oy = (y0 + wv) >> 1;
      if (oy < OHp) {
#pragma unroll
        for (int Mt = 0; Mt < 2; ++Mt)
#pragma unroll
          for (int i = 0; i < 8; ++i) {
            int pxl = Mt * 16 + (i >> 1) * 4 + (i & 1) + 2 * lh;
            int ox = (x0 >> 1) + pxl;
            if (ox < OWp) {
#pragma unroll
              for (int nt = 0; nt < NT; ++nt) {
                float v = fmaxf(
                    hm[Mt][nt][i],
                    pl[((((wv >> 1) * 2 + Mt) * NT + nt) * 8 + i) * 64 + lane]);
                int oc = (z * NT + nt) * 32 + lc;
                obf[((size_t)oy * OWp + ox) * Ntot + oc] = f2bf(v);
              }
            }
          }
      }
    }
  }
}

// ------------------------------------------------------------------
// Head reduce: sum nz HWC(x32) fp32 partial slices -> 24 CHW planes.
// ------------------------------------------------------------------

__global__ __launch_bounds__(256) void head_reduce(const float* __restrict__ hp,
                                                   float* __restrict__ out, int HW,
                                                   int nz) {
  __shared__ float t[256 * 33];
  int tid = threadIdx.x;
  int sp0 = blockIdx.x * 256;
  int lim = (HW - sp0) * 32;
#pragma unroll 4
  for (int i = 0; i < 32; ++i) {
    int e = i * 256 + tid;
    float s = 0.f;
    if (e < lim) {
      size_t gidx = (size_t)sp0 * 32 + e;
      for (int z = 0; z < nz; ++z) s += hp[(size_t)z * HW * 32 + gidx];
    }
    t[(e >> 5) * 33 + (e & 31)] = s;
  }
  __syncthreads();
  int sp = sp0 + tid;
  if (sp < HW) {
#pragma unroll
    for (int ch = 0; ch < 24; ++ch)
      out[(size_t)ch * HW + sp] = t[tid * 33 + ch];
  }
}

// ------------------------------------------------------------------

extern "C" void kernel_launch(void* const* d_in, const int* in_sizes, int n_in,
                              void* d_out, int out_size, void* d_ws, size_t ws_size,
                              hipStream_t stream) {
  (void)in_sizes; (void)n_in; (void)out_size; (void)ws_size;
  const float* pillars = (const float*)d_in[0];
  const int* coords = (const int*)d_in[1];
  const float* lin_w = (const float*)d_in[2];
  const float* lin_b = (const float*)d_in[3];
  const float* pfn_g = (const float*)d_in[4];
  const float* pfn_b = (const float*)d_in[5];
  const float* c1_w = (const float*)d_in[6];
  const float* c1_b = (const float*)d_in[7];
  const float* bn1_g = (const float*)d_in[8];
  const float* bn1_b = (const float*)d_in[9];
  const float* c2_w = (const float*)d_in[10];
  const float* c2_b = (const float*)d_in[11];
  const float* bn2_g = (const float*)d_in[12];
  const float* bn2_b = (const float*)d_in[13];
  const float* h1_w = (const float*)d_in[14];
  const float* h1_b = (const float*)d_in[15];
  const float* hbn_g = (const float*)d_in[16];
  const float* hbn_b = (const float*)d_in[17];
  const float* hb_w = (const float*)d_in[18];
  const float* hb_b = (const float*)d_in[19];
  const float* hc_w = (const float*)d_in[20];
  const float* hc_b = (const float*)d_in[21];
  float* out = (float*)d_out;

  // ---- workspace layout (bytes) ----
  char* ws = (char*)d_ws;
  float* mom     = (float*)(ws + 0);          // 216 B
  float* pfn_ss  = (float*)(ws + 512);        // 512 B
  float* bn_acc1 = (float*)(ws + 1024);       // 2048 B
  float* bn_acc2 = (float*)(ws + 3072);       // 2048 B
  float* bn_acc3 = (float*)(ws + 5120);       // 2048 B
  float* coef1   = (float*)(ws + 7168);       // 512 B
  float* coef2   = (float*)(ws + 7680);       // 1024 B
  float* coef3   = (float*)(ws + 8704);       // 2048 B
  ushort_t* zbuf = (ushort_t*)(ws + 10752);   // 512 B zeroed scratch page
  int* winner    = (int*)(ws + 11264);        // 1774224 B
  ushort_t* feats  = (ushort_t*)(ws + 1785600);    // 20000x64 bf16 = 2560000 B
  ushort_t* c1p    = (ushort_t*)(ws + 4345600);    // 333x333x64  = 14193792 B (raw pooled)
  ushort_t* c2a    = (ushort_t*)(ws + 4345600);    // alias: c1p dead after bnrelu1
  ushort_t* c2p    = (ushort_t*)(ws + 18539392);   // 166x166x128 = 7054336 B (raw pooled)
  ushort_t* h1out  = (ushort_t*)(ws + 25593728);   // 166x166x256 = 14108672 B (raw)
  ushort_t* w2c1   = (ushort_t*)(ws + 39702400);   // 73728 B
  ushort_t* w2c2   = (ushort_t*)(ws + 39776128);   // 147456 B
  ushort_t* w2h1   = (ushort_t*)(ws + 39923584);   // 589824 B
  ushort_t* w2hd   = (ushort_t*)(ws + 40513408);   // 147456 B
  float* hpart     = (float*)(ws + 40660864);      // 4x27556x32x4 = 14108672 B
  ushort_t* c1a    = (ushort_t*)(ws + 54769536);   // 14193792 B
  ushort_t* h1a    = (ushort_t*)(ws + 54769536);   // alias: c1a dead after conv2

  const int HW3 = 166 * 166;

  // ---- upfront zero-init (covers mom..zbuf) ----
  hipMemsetAsync(ws, 0, 11264, stream);
  hipMemsetAsync(winner, 0xFF, 1774224, stream);

  // ---- weight prep (merged) ----
  prep_all<<<234, 256, 0, stream>>>(c1_w, c2_w, h1_w, hb_w, hc_w, w2c1, w2c2, w2h1,
                                    w2hd);

  // ---- PFN: moments-based stats, then feats ----
  pillar_moments<<<128, 512, 0, stream>>>(pillars, mom);
  pfn_finalize<<<1, 64, 0, stream>>>(mom, lin_w, lin_b, pfn_g, pfn_b, pfn_ss);
  pfn_feats<<<5000, 256, 0, stream>>>(pillars, lin_w, lin_b, pfn_ss, feats);

  // ---- scatter winner map ----
  scatter_winner<<<(20000 + 255) / 256, 256, 0, stream>>>(coords, winner, 20000);

  // ---- conv1: gather via gload_lds pipeline, stats+pool -> c1p (raw) ----
  conv_mfma<2, 8, true, false, true, true><<<dim3(11, 84, 1), 512, 0, stream>>>(
      nullptr, winner, feats, w2c1, c1_b, nullptr, zbuf, c1p, nullptr, bn_acc1, 666,
      666, 64, 2, 2);
  bn_make_coefs<<<1, 64, 0, stream>>>(bn_acc1, bn1_g, bn1_b, 1.f / 443556.f, coef1, 64);

  // ---- bnrelu1: c1p raw -> c1a ready ----
  bnrelu<<<(887112 + 255) / 256, 256, 0, stream>>>(c1p, coef1, 64, 887112, c1a);

  // ---- conv2: linear gload_lds pipeline from c1a, stats+pool -> c2p (raw) ----
  conv_mfma<2, 8, false, false, true, true><<<dim3(6, 42, 2), 512, 0, stream>>>(
      c1a, nullptr, nullptr, w2c2, c2_b, nullptr, zbuf, c2p, nullptr, bn_acc2, 333, 333,
      64, 2, 4);
  bn_make_coefs<<<1, 128, 0, stream>>>(bn_acc2, bn2_g, bn2_b, 1.f / 110889.f, coef2, 128);

  // ---- bnrelu2: c2p raw -> c2a ready (aliases dead c1p) ----
  bnrelu<<<(440896 + 255) / 256, 256, 0, stream>>>(c2p, coef2, 128, 440896, c2a);

  // ---- h1: linear pipeline from c2a, NT=2 WAVES=4 oc-split z=4 (stats) ----
  conv_mfma<2, 4, false, false, true, false><<<dim3(3, 42, 4), 256, 0, stream>>>(
      c2a, nullptr, nullptr, w2h1, h1_b, nullptr, zbuf, h1out, nullptr, bn_acc3, 166,
      166, 128, 4, 8);
  bn_make_coefs<<<1, 256, 0, stream>>>(bn_acc3, hbn_g, hbn_b, 1.f / 27556.f, coef3, 256);

  // ---- bnrelu3: h1out raw -> h1a ready (aliases dead c1a) ----
  bnrelu<<<(881792 + 255) / 256, 256, 0, stream>>>(h1out, coef3, 256, 881792, h1a);

  // ---- heads: linear pipeline from h1a, K-split z=4, coalesced partials ----
  conv_mfma<1, 4, false, true, false, false><<<dim3(3, 42, 4), 256, 0, stream>>>(
      h1a, nullptr, nullptr, w2hd, hb_b, hc_b, zbuf, nullptr, hpart, nullptr, 166,
      166, 256, 2, 1);
  head_reduce<<<(HW3 + 255) / 256, 256, 0, stream>>>(hpart, out, HW3, 4);
}